// Round 12
// baseline (223.203 us; speedup 1.0000x reference)
//
#include <hip/hip_runtime.h>
#include <stdint.h>

// FANeuron two-pass:
//  K1 (scan): sequential recurrence, compute-only. 64-thread block = 128
//             chains (2 batch rows x 64 features). Hand-pipelined inline-asm:
//             each 12-instr period retires one step of BOTH chains; the
//             second chain fills the first chain's dep-latency shadows
//             (6-instr step is dep-bound, not issue-bound -> 2 chains free).
//             Depth-2-prefetch global_load_lds ring, counted vmcnt(32).
//             Refractory via per-chain 32-step window bitmap (rs>=31).
//  K2 (emit): one thread per (4 features, chunk); float4 loads/stores,
//             replays chunks bit-exactly from (ema, nr) seeds.

#define L_CHUNK 256
#define TS 64          // timesteps per K1 tile
#define DEPTH 4        // LDS ring slots
#define K2_UNROLL 8

typedef const __attribute__((address_space(1))) uint32_t* gptr_t;
typedef __attribute__((address_space(3))) uint32_t* lptr_t;

// One pipelined period: step j of chain A and chain B (skewed schedule:
// updates ema to step j+1 while finishing step j's d2/cmp/append).
// All dep gaps >= 3 instr (6 cyc). Rounding = separately-rounded f32.
#define FA_PER(AJ, AJ1, BJ, BJ1)                                   \
    "v_sub_f32 %[d1a], %[" #AJ1 "], %[emA]\n\t"                    \
    "v_sub_f32 %[d1b], %[" #BJ1 "], %[emB]\n\t"                    \
    "v_sub_f32 %[d2a], %[" #AJ "], %[emA]\n\t"                     \
    "v_sub_f32 %[d2b], %[" #BJ "], %[emB]\n\t"                     \
    "v_mul_f32 %[ama], %[al], %[d1a]\n\t"                          \
    "v_mul_f32 %[amb], %[al], %[d1b]\n\t"                          \
    "v_cmp_le_f32_e64 vcc, %[th], |%[d2a]|\n\t"                    \
    "v_addc_co_u32 %[bA], vcc, %[bA], %[bA], vcc\n\t"              \
    "v_add_f32 %[emA], %[emA], %[ama]\n\t"                         \
    "v_cmp_le_f32_e64 vcc, %[th], |%[d2b]|\n\t"                    \
    "v_addc_co_u32 %[bB], vcc, %[bB], %[bB], vcc\n\t"              \
    "v_add_f32 %[emB], %[emB], %[amb]\n\t"

// 8 steps of BOTH chains (16 chain-steps), hand-pipelined.
#define FA_ASM8_2(PA_, PB_)                                        \
    asm volatile(                                                  \
        /* prologue: step-0 ema updates */                         \
        "v_sub_f32 %[d1a], %[A0], %[emA]\n\t"                      \
        "v_sub_f32 %[d1b], %[B0], %[emB]\n\t"                      \
        "v_mul_f32 %[ama], %[al], %[d1a]\n\t"                      \
        "v_mul_f32 %[amb], %[al], %[d1b]\n\t"                      \
        "v_add_f32 %[emA], %[emA], %[ama]\n\t"                     \
        "v_add_f32 %[emB], %[emB], %[amb]\n\t"                     \
        FA_PER(A0, A1, B0, B1)                                     \
        FA_PER(A1, A2, B1, B2)                                     \
        FA_PER(A2, A3, B2, B3)                                     \
        FA_PER(A3, A4, B3, B4)                                     \
        FA_PER(A4, A5, B4, B5)                                     \
        FA_PER(A5, A6, B5, B6)                                     \
        FA_PER(A6, A7, B6, B7)                                     \
        /* epilogue: step-7 d2/cmp/append */                       \
        "v_sub_f32 %[d2a], %[A7], %[emA]\n\t"                      \
        "v_sub_f32 %[d2b], %[B7], %[emB]\n\t"                      \
        "v_cmp_le_f32_e64 vcc, %[th], |%[d2a]|\n\t"                \
        "v_addc_co_u32 %[bA], vcc, %[bA], %[bA], vcc\n\t"          \
        "v_cmp_le_f32_e64 vcc, %[th], |%[d2b]|\n\t"                \
        "v_addc_co_u32 %[bB], vcc, %[bB], %[bB], vcc"              \
        : [emA]"+v"(emaA), [emB]"+v"(emaB),                        \
          [bA]"+v"(bitsA), [bB]"+v"(bitsB),                        \
          [d1a]"=&v"(td1a), [d1b]"=&v"(td1b),                      \
          [d2a]"=&v"(td2a), [d2b]"=&v"(td2b),                      \
          [ama]"=&v"(tama), [amb]"=&v"(tamb)                       \
        : [A0]"v"((PA_)[0]), [A1]"v"((PA_)[1]), [A2]"v"((PA_)[2]), \
          [A3]"v"((PA_)[3]), [A4]"v"((PA_)[4]), [A5]"v"((PA_)[5]), \
          [A6]"v"((PA_)[6]), [A7]"v"((PA_)[7]),                    \
          [B0]"v"((PB_)[0]), [B1]"v"((PB_)[1]), [B2]"v"((PB_)[2]), \
          [B3]"v"((PB_)[3]), [B4]"v"((PB_)[4]), [B5]"v"((PB_)[5]), \
          [B6]"v"((PB_)[6]), [B7]"v"((PB_)[7]),                    \
          [th]"v"(thf), [al]"s"(alpha)                             \
        : "vcc")

#define FA_RESOLVE(BITS, NR, BASE)                                         \
    do {                                                                   \
        uint32_t rv = __brev(BITS);   /* bit j = cross at (BASE)+j */      \
        int rel = (NR) - (BASE);                                           \
        uint32_t keep = (rel <= 0) ? rv                                    \
                      : ((rel >= 32) ? 0u : (rv & (0xFFFFFFFFu << rel)));  \
        int j1 = __ffs(keep);                                              \
        NR = keep ? ((BASE) + j1 + rs) : (NR);   /* t+1+rs */              \
        BITS = 0;                                                          \
    } while (0)

__global__ __launch_bounds__(64, 1)
void fa_scan_kernel(const float* __restrict__ x,
                    const float* __restrict__ vb,
                    const float* __restrict__ A,
                    const float* __restrict__ th,
                    const float* __restrict__ gain,
                    const float* __restrict__ tref,
                    float* __restrict__ emas,   // [nchunks][N] (c>=1 used)
                    int*   __restrict__ nrs,    // [nchunks][N] (c>=1 used)
                    int B, int T, int F) {
#pragma clang fp contract(off)
    __shared__ float lds[DEPTH][2][TS][64];     // 128 KiB
    const int lane = threadIdx.x;
    const int gpb = F >> 6;
    const int halfB = B >> 1;
    const int bi = blockIdx.x;
    const int p = bi / gpb;
    const int g = bi - p * gpb;
    const int f = (g << 6) + lane;
    const int b0 = p, b1 = p + halfB;
    const int i0 = b0 * F + f;
    const int i1 = b1 * F + f;
    const int N = B * F;

    const float vbf = vb[f], Af = A[f], thf = th[f], gf = gain[f];
    const float alpha = 0.001f;                 // f32(0.05/50)
    const int rs = (int)fmaxf(ceilf(tref[f] / 0.05f), 1.0f);

    const size_t lane_off = (size_t)(lane >> 4) * F + ((lane & 15) << 2);
    const float* g0 = x + (size_t)b0 * T * F + (size_t)(g << 6) + lane_off;
    const float* g1 = x + (size_t)b1 * T * F + (size_t)(g << 6) + lane_off;
    const int ntiles = T / TS;

#define ISSUE_TILE(J)                                                         \
    do {                                                                      \
        const float* sa_ = g0 + (size_t)(J) * TS * F;                         \
        const float* sb_ = g1 + (size_t)(J) * TS * F;                         \
        float* da_ = &lds[(J) & (DEPTH - 1)][0][0][0];                        \
        float* db_ = &lds[(J) & (DEPTH - 1)][1][0][0];                        \
        _Pragma("unroll")                                                     \
        for (int jj = 0; jj < 16; ++jj)                                       \
            __builtin_amdgcn_global_load_lds(                                 \
                (gptr_t)(sa_ + (size_t)(4 * jj) * F),                         \
                (lptr_t)(da_ + 4 * jj * 64), 16, 0, 0);                       \
        _Pragma("unroll")                                                     \
        for (int jj = 0; jj < 16; ++jj)                                       \
            __builtin_amdgcn_global_load_lds(                                 \
                (gptr_t)(sb_ + (size_t)(4 * jj) * F),                         \
                (lptr_t)(db_ + 4 * jj * 64), 16, 0, 0);                       \
    } while (0)

    ISSUE_TILE(0);
    ISSUE_TILE(1);

    // fast path requires rs>=31 (max one fire per 32-step window)
    bool fastAll = __all((gf == 1.0f) && (Af == 1.0f) && (vbf == 0.0f) &&
                         (rs >= 31));

    float emaA = 0.0f, emaB = 0.0f;
    int nrA = 0, nrB = 0;                        // ABSOLUTE next-ready step
    uint32_t bitsA = 0, bitsB = 0;
    float td1a, td1b, td2a, td2b, tama, tamb;

    float PA[8], PB[8], QA[8], QB[8];

#define LOAD16(DA, DB, T0)                                                    \
    do {                                                                      \
        _Pragma("unroll")                                                     \
        for (int j = 0; j < 8; ++j) {                                         \
            (DA)[j] = lds[slot][0][(T0) + j][lane];                           \
            (DB)[j] = lds[slot][1][(T0) + j][lane];                           \
        }                                                                     \
    } while (0)

    for (int k = 0; k < ntiles; ++k) {
        if (k < ntiles - 1) asm volatile("s_waitcnt vmcnt(32)" ::: "memory");
        else                asm volatile("s_waitcnt vmcnt(0)"  ::: "memory");
        __builtin_amdgcn_sched_barrier(0);

        const int slot = k & (DEPTH - 1);
        const int tb = k * TS;

        if (k == 0) {
            // bit-exact t==0 seeding: ema = xt(0); step-0 prologue then
            // computes d1=0, am=0, ema+0=ema -> matches reference exactly.
            float xa = lds[0][0][0][lane];
            float xb = lds[0][1][0][lane];
            emaA = fastAll ? xa : (xa * gf);
            emaB = fastAll ? xb : (xb * gf);
        } else if ((k & 3) == 0) {               // L_CHUNK/TS == 4
            int c = k >> 2;
            emas[(size_t)c * N + i0] = emaA;
            nrs[(size_t)c * N + i0] = nrA;
            emas[(size_t)c * N + i1] = emaB;
            nrs[(size_t)c * N + i1] = nrB;
        }

        if (fastAll) {
            LOAD16(PA, PB, 0);
            LOAD16(QA, QB, 8);
            FA_ASM8_2(PA, PB);                   // steps 0-7
            LOAD16(PA, PB, 16);
            FA_ASM8_2(QA, QB);                   // 8-15
            LOAD16(QA, QB, 24);
            FA_ASM8_2(PA, PB);                   // 16-23
            LOAD16(PA, PB, 32);
            FA_ASM8_2(QA, QB);                   // 24-31
            FA_RESOLVE(bitsA, nrA, tb);
            FA_RESOLVE(bitsB, nrB, tb);
            LOAD16(QA, QB, 40);
            FA_ASM8_2(PA, PB);                   // 32-39
            LOAD16(PA, PB, 48);
            FA_ASM8_2(QA, QB);                   // 40-47
            LOAD16(QA, QB, 56);
            FA_ASM8_2(PA, PB);                   // 48-55
            FA_ASM8_2(QA, QB);                   // 56-63
            FA_RESOLVE(bitsA, nrA, tb + 32);
            FA_RESOLVE(bitsB, nrB, tb + 32);
        } else {
            // general params: compiler-scheduled 2-chain loop (correct path)
#pragma unroll
            for (int t8 = 0; t8 < TS / 8; ++t8) {
                const int slot_ = slot;
#pragma unroll
                for (int j = 0; j < 8; ++j) {
                    const int t = tb + t8 * 8 + j;
                    {
                        float xt = lds[slot_][0][t8 * 8 + j][lane] * gf;
                        float d1 = xt - emaA;
                        float am = alpha * d1;
                        emaA = emaA + am;
                        float d2 = xt - emaA;
                        float av = Af * d2;
                        float vc = vbf - av;
                        float dv = vc - vbf;
                        bool cross = fabsf(dv) >= thf;
                        bool tge = t >= nrA;
                        bool fired = cross && tge;
                        nrA = fired ? (t + 1 + rs) : nrA;
                    }
                    {
                        float xt = lds[slot_][1][t8 * 8 + j][lane] * gf;
                        float d1 = xt - emaB;
                        float am = alpha * d1;
                        emaB = emaB + am;
                        float d2 = xt - emaB;
                        float av = Af * d2;
                        float vc = vbf - av;
                        float dv = vc - vbf;
                        bool cross = fabsf(dv) >= thf;
                        bool tge = t >= nrB;
                        bool fired = cross && tge;
                        nrB = fired ? (t + 1 + rs) : nrB;
                    }
                }
            }
        }

        if (k + 2 < ntiles) ISSUE_TILE(k + 2);
    }
#undef ISSUE_TILE
#undef LOAD16
}

__global__ __launch_bounds__(256)
void fa_emit_kernel(const float* __restrict__ x,
                    const float* __restrict__ vb,
                    const float* __restrict__ A,
                    const float* __restrict__ th,
                    const float* __restrict__ gain,
                    const float* __restrict__ tref,
                    const float* __restrict__ emas,
                    const int*   __restrict__ nrs,
                    float* __restrict__ out,
                    int B, int T, int F, int nchunks) {
#pragma clang fp contract(off)
    const int N = B * F, N4 = N >> 2, F4 = F >> 2;
    int tid = blockIdx.x * blockDim.x + threadIdx.x;
    if (tid >= N4 * nchunks) return;
    int k = tid / N4;
    int i4 = tid - k * N4;
    int fi = i4 % F4;
    int b = i4 / F4;
    int f0 = fi << 2;

    float vbv[4], Av[4], thv[4], gv[4];
    int rsv[4];
    *(float4*)vbv = *(const float4*)&vb[f0];
    *(float4*)Av  = *(const float4*)&A[f0];
    *(float4*)thv = *(const float4*)&th[f0];
    *(float4*)gv  = *(const float4*)&gain[f0];
    {
        float trv[4];
        *(float4*)trv = *(const float4*)&tref[f0];
#pragma unroll
        for (int c = 0; c < 4; ++c)
            rsv[c] = (int)fmaxf(ceilf(trv[c] / 0.05f), 1.0f);
    }
    const float alpha = 0.001f;

    const float* xp = x + (size_t)b * T * F + f0;
    float* va_o = out + (size_t)b * (T + 1) * F + f0;
    float* sp_o = out + (size_t)B * (T + 1) * F + (size_t)b * (T + 1) * F + f0;

    int tbeg = k * L_CHUNK;
    int tend = tbeg + L_CHUNK;
    if (tend > T) tend = T;

    float4 cur[K2_UNROLL], nxt[K2_UNROLL];
#pragma unroll
    for (int u = 0; u < K2_UNROLL; ++u)
        cur[u] = *(const float4*)&xp[(size_t)(tbeg + u) * F];

    float e[4];
    int nr4[4];
    if (k == 0) {
        float x0[4];
        *(float4*)x0 = cur[0];
#pragma unroll
        for (int c = 0; c < 4; ++c) { e[c] = x0[c] * gv[c]; nr4[c] = 0; }
        *(float4*)&va_o[0] = *(const float4*)vbv;   // va_trace[:,0,:] = vb
    } else {
        *(float4*)e = *(const float4*)&emas[(size_t)k * N + (size_t)b * F + f0];
        *(int4*)nr4 = *(const int4*)&nrs[(size_t)k * N + (size_t)b * F + f0];
    }

    float last4[4] = {0.f, 0.f, 0.f, 0.f};
    for (int t0 = tbeg; t0 < tend; t0 += K2_UNROLL) {
        if (t0 + K2_UNROLL < tend) {
#pragma unroll
            for (int u = 0; u < K2_UNROLL; ++u)
                nxt[u] = *(const float4*)&xp[(size_t)(t0 + K2_UNROLL + u) * F];
        }
#pragma unroll
        for (int u = 0; u < K2_UNROLL; ++u) {
            int t = t0 + u;
            float xs[4], va4[4], sp4[4];
            *(float4*)xs = cur[u];
#pragma unroll
            for (int c = 0; c < 4; ++c) {
                float xt = xs[c] * gv[c];
                float d1 = xt - e[c];
                float am = alpha * d1;
                e[c] = e[c] + am;
                float d2 = xt - e[c];
                float av = Av[c] * d2;
                float vc = vbv[c] - av;       // va_cand
                float dv = vc - vbv[c];
                bool cross = fabsf(dv) >= thv[c];
                bool tge = t >= nr4[c];
                bool fired = cross && tge;
                va4[c] = (cross || !tge) ? vbv[c] : vc;
                nr4[c] = fired ? (t + 1 + rsv[c]) : nr4[c];
                sp4[c] = fired ? 1.0f : 0.0f;
                last4[c] = sp4[c];
            }
            *(float4*)&va_o[(size_t)(t + 1) * F] = *(const float4*)va4;
            *(float4*)&sp_o[(size_t)t * F] = *(const float4*)sp4;
        }
#pragma unroll
        for (int u = 0; u < K2_UNROLL; ++u) cur[u] = nxt[u];
    }
    if (tend == T)                              // spikes[:,T,:] = fired_{T-1}
        *(float4*)&sp_o[(size_t)T * F] = *(const float4*)last4;
}

// Fallback: monolithic (used only if ws too small / shape odd).
__global__ __launch_bounds__(64, 1)
void fa_neuron_mono(const float* __restrict__ x,
                    const float* __restrict__ vb,
                    const float* __restrict__ A,
                    const float* __restrict__ th,
                    const float* __restrict__ gain,
                    const float* __restrict__ tref,
                    float* __restrict__ out,
                    int B, int T, int F) {
#pragma clang fp contract(off)
    int tid = blockIdx.x * blockDim.x + threadIdx.x;
    if (tid >= B * F) return;
    int f = tid % F;
    int b = tid / F;
    const float vbf = vb[f], Af = A[f], thf = th[f], gf = gain[f];
    const float alpha = 0.001f;
    int rs = (int)fmaxf(ceilf(tref[f] / 0.05f), 1.0f);
    const float* xp = x + (size_t)b * T * F + f;
    float* va_out   = out + (size_t)b * (T + 1) * F + f;
    float* sp_out   = out + (size_t)B * (T + 1) * F + (size_t)b * (T + 1) * F + f;
    va_out[0] = vbf;
    float ema = 0.0f;
    int nr = 0;
    for (int t = 0; t < T; ++t) {
        float xt = xp[(size_t)t * F] * gf;
        if (t == 0) {
            ema = xt;
        } else {
            float d1 = xt - ema;
            float am = alpha * d1;
            ema = ema + am;
        }
        float d2 = xt - ema;
        float av = Af * d2;
        float vc = vbf - av;
        float dv = vc - vbf;
        bool cross = fabsf(dv) >= thf;
        bool tge = t >= nr;
        bool fired = cross && tge;
        float va_next = (cross || !tge) ? vbf : vc;
        nr = fired ? (t + 1 + rs) : nr;
        float spv = fired ? 1.0f : 0.0f;
        va_out[(size_t)(t + 1) * F] = va_next;
        sp_out[(size_t)t * F] = spv;
        if (t == T - 1) sp_out[(size_t)T * F] = spv;
    }
}

extern "C" void kernel_launch(void* const* d_in, const int* in_sizes, int n_in,
                              void* d_out, int out_size, void* d_ws, size_t ws_size,
                              hipStream_t stream) {
    const float* x    = (const float*)d_in[0];
    const float* vb   = (const float*)d_in[1];
    const float* A    = (const float*)d_in[2];
    const float* th   = (const float*)d_in[3];
    const float* gain = (const float*)d_in[4];
    const float* tref = (const float*)d_in[5];
    float* out = (float*)d_out;

    int F = in_sizes[1];                                   // 512
    long long BF = (long long)out_size / 2 - in_sizes[0];  // B*F
    int B = (int)(BF / F);                                 // 16
    int T = (int)(in_sizes[0] / BF);                       // 4096
    int N = B * F;

    int nchunks = (T + L_CHUNK - 1) / L_CHUNK;
    size_t ws_need = (size_t)nchunks * N * (sizeof(float) + sizeof(int));

    bool tiled_ok = (ws_size >= ws_need) && (T % L_CHUNK == 0) &&
                    (T % TS == 0) && (T / TS >= 4) && (F % 64 == 0) &&
                    (F % 4 == 0) && (B % 2 == 0) && (L_CHUNK == 4 * TS) &&
                    ((N / 4) % 256 == 0);

    if (!tiled_ok) {
        int block = 64;
        int grid = (N + block - 1) / block;
        fa_neuron_mono<<<grid, block, 0, stream>>>(x, vb, A, th, gain, tref, out, B, T, F);
        return;
    }

    float* emas = (float*)d_ws;
    int*   nrs  = (int*)(emas + (size_t)nchunks * N);

    {
        int block = 64;
        int grid = (B / 2) * (F / 64);   // 2 chains per lane
        fa_scan_kernel<<<grid, block, 0, stream>>>(x, vb, A, th, gain, tref,
                                                   emas, nrs, B, T, F);
    }
    {
        int total = (N / 4) * nchunks;
        int block = 256;
        int grid = (total + block - 1) / block;
        fa_emit_kernel<<<grid, block, 0, stream>>>(x, vb, A, th, gain, tref,
                                                   emas, nrs, out, B, T, F, nchunks);
    }
}

// Round 13
// 151.661 us; speedup vs baseline: 1.4717x; 1.4717x over previous
//
#include <hip/hip_runtime.h>
#include <stdint.h>

// FANeuron two-pass:
//  K1 (scan): sequential per-chain recurrence, compute-only. 64-thread block
//             = 64 chains. Depth-4 global_load_lds ring, counted vmcnt(32).
//             FAST PATH: hand-scheduled inline-asm pipeline, 6 instr/step.
//             Refractory via 32-step window bitmap (valid: rs>=31).
//             Seeds (ema, nr) stored every (1<<lsi) tiles.
//  K2 (emit): one thread per (chain, chunk) replays its chunk bit-exactly
//             from the seeded (ema, nr) state and writes va_trace + spikes.
//             Chunk size adaptive (128 if ws allows, else 256).

#define TS 64          // timesteps per K1 tile
#define DEPTH 4        // LDS ring slots
#define K2_UNROLL 8

typedef const __attribute__((address_space(1))) uint32_t* gptr_t;
typedef __attribute__((address_space(3))) uint32_t* lptr_t;

// 8 bit-exact steps, hand-pipelined. ema/bits carried; vcc clobbered.
#define FA_ASM8(A)                                                         \
    asm volatile(                                                          \
        "v_sub_f32 %[d1], %[a0], %[ema]\n\t"                               \
        "v_mul_f32 %[am], %[al], %[d1]\n\t"                                \
        "v_add_f32 %[ema], %[ema], %[am]\n\t"                              \
        "v_sub_f32 %[d1], %[a1], %[ema]\n\t"                               \
        "v_sub_f32 %[d2], %[a0], %[ema]\n\t"                               \
        "v_mul_f32 %[am], %[al], %[d1]\n\t"                                \
        "v_cmp_le_f32_e64 vcc, %[th], |%[d2]|\n\t"                         \
        "v_add_f32 %[ema], %[ema], %[am]\n\t"                              \
        "v_addc_co_u32 %[bits], vcc, %[bits], %[bits], vcc\n\t"            \
        "v_sub_f32 %[d1], %[a2], %[ema]\n\t"                               \
        "v_sub_f32 %[d2], %[a1], %[ema]\n\t"                               \
        "v_mul_f32 %[am], %[al], %[d1]\n\t"                                \
        "v_cmp_le_f32_e64 vcc, %[th], |%[d2]|\n\t"                         \
        "v_add_f32 %[ema], %[ema], %[am]\n\t"                              \
        "v_addc_co_u32 %[bits], vcc, %[bits], %[bits], vcc\n\t"            \
        "v_sub_f32 %[d1], %[a3], %[ema]\n\t"                               \
        "v_sub_f32 %[d2], %[a2], %[ema]\n\t"                               \
        "v_mul_f32 %[am], %[al], %[d1]\n\t"                                \
        "v_cmp_le_f32_e64 vcc, %[th], |%[d2]|\n\t"                         \
        "v_add_f32 %[ema], %[ema], %[am]\n\t"                              \
        "v_addc_co_u32 %[bits], vcc, %[bits], %[bits], vcc\n\t"            \
        "v_sub_f32 %[d1], %[a4], %[ema]\n\t"                               \
        "v_sub_f32 %[d2], %[a3], %[ema]\n\t"                               \
        "v_mul_f32 %[am], %[al], %[d1]\n\t"                                \
        "v_cmp_le_f32_e64 vcc, %[th], |%[d2]|\n\t"                         \
        "v_add_f32 %[ema], %[ema], %[am]\n\t"                              \
        "v_addc_co_u32 %[bits], vcc, %[bits], %[bits], vcc\n\t"            \
        "v_sub_f32 %[d1], %[a5], %[ema]\n\t"                               \
        "v_sub_f32 %[d2], %[a4], %[ema]\n\t"                               \
        "v_mul_f32 %[am], %[al], %[d1]\n\t"                                \
        "v_cmp_le_f32_e64 vcc, %[th], |%[d2]|\n\t"                         \
        "v_add_f32 %[ema], %[ema], %[am]\n\t"                              \
        "v_addc_co_u32 %[bits], vcc, %[bits], %[bits], vcc\n\t"            \
        "v_sub_f32 %[d1], %[a6], %[ema]\n\t"                               \
        "v_sub_f32 %[d2], %[a5], %[ema]\n\t"                               \
        "v_mul_f32 %[am], %[al], %[d1]\n\t"                                \
        "v_cmp_le_f32_e64 vcc, %[th], |%[d2]|\n\t"                         \
        "v_add_f32 %[ema], %[ema], %[am]\n\t"                              \
        "v_addc_co_u32 %[bits], vcc, %[bits], %[bits], vcc\n\t"            \
        "v_sub_f32 %[d1], %[a7], %[ema]\n\t"                               \
        "v_sub_f32 %[d2], %[a6], %[ema]\n\t"                               \
        "v_mul_f32 %[am], %[al], %[d1]\n\t"                                \
        "v_cmp_le_f32_e64 vcc, %[th], |%[d2]|\n\t"                         \
        "v_add_f32 %[ema], %[ema], %[am]\n\t"                              \
        "v_addc_co_u32 %[bits], vcc, %[bits], %[bits], vcc\n\t"            \
        "v_sub_f32 %[d2], %[a7], %[ema]\n\t"                               \
        "v_cmp_le_f32_e64 vcc, %[th], |%[d2]|\n\t"                         \
        "v_addc_co_u32 %[bits], vcc, %[bits], %[bits], vcc"                \
        : [ema]"+v"(ema), [bits]"+v"(bits),                                \
          [d1]"=&v"(td1), [d2]"=&v"(td2), [am]"=&v"(tam)                   \
        : [a0]"v"((A)[0]), [a1]"v"((A)[1]), [a2]"v"((A)[2]),               \
          [a3]"v"((A)[3]), [a4]"v"((A)[4]), [a5]"v"((A)[5]),               \
          [a6]"v"((A)[6]), [a7]"v"((A)[7]),                                \
          [th]"v"(thf), [al]"s"(alpha)                                     \
        : "vcc")

#define FA_RESOLVE(BASE)                                                   \
    do {                                                                   \
        uint32_t rv = __brev(bits);   /* bit j = cross at (BASE)+j */      \
        int rel = nr - (BASE);                                             \
        uint32_t keep = (rel <= 0) ? rv                                    \
                      : ((rel >= 32) ? 0u : (rv & (0xFFFFFFFFu << rel)));  \
        int j1 = __ffs(keep);                                              \
        nr = keep ? ((BASE) + j1 + rs) : nr;   /* t+1+rs */                \
        bits = 0;                                                          \
    } while (0)

__global__ __launch_bounds__(64, 1)
void fa_scan_kernel(const float* __restrict__ x,
                    const float* __restrict__ vb,
                    const float* __restrict__ A,
                    const float* __restrict__ th,
                    const float* __restrict__ gain,
                    const float* __restrict__ tref,
                    float* __restrict__ emas,   // [nchunks][N] (c>=1 used)
                    int*   __restrict__ nrs,    // [nchunks][N] (c>=1 used)
                    int B, int T, int F, int lsi) {   // lsi = log2(tiles/chunk)
#pragma clang fp contract(off)
    __shared__ float lds[DEPTH][TS][64];
    const int lane = threadIdx.x;
    const int gpb = F >> 6;
    const int bi = blockIdx.x;
    const int b = bi / gpb;
    const int f0 = (bi - b * gpb) << 6;
    const int f = f0 + lane;
    const int i = b * F + f;
    const int N = B * F;

    const float vbf = vb[f], Af = A[f], thf = th[f], gf = gain[f];
    const float alpha = 0.001f;                 // f32(0.05/50)
    const int rs = (int)fmaxf(ceilf(tref[f] / 0.05f), 1.0f);

    const float* xb = x + (size_t)b * T * F + f0;
    const float* gsrc0 = xb + (size_t)(lane >> 4) * F + ((lane & 15) << 2);
    const int ntiles = T / TS;
    const int simask = (1 << lsi) - 1;

#define ISSUE_TILE(J)                                                         \
    do {                                                                      \
        const float* s_ = gsrc0 + (size_t)(J) * TS * F;                       \
        float* d_ = &lds[(J) & (DEPTH - 1)][0][0];                            \
        _Pragma("unroll")                                                     \
        for (int jj = 0; jj < 16; ++jj) {                                     \
            __builtin_amdgcn_global_load_lds(                                 \
                (gptr_t)(s_ + (size_t)(4 * jj) * F),                          \
                (lptr_t)(d_ + 4 * jj * 64), 16, 0, 0);                        \
        }                                                                     \
    } while (0)

    ISSUE_TILE(0);
    ISSUE_TILE(1);
    ISSUE_TILE(2);

    // fast path requires rs>=31 (max one fire per 32-step window)
    bool fastAll = __all((gf == 1.0f) && (Af == 1.0f) && (vbf == 0.0f) &&
                         (rs >= 31));

    float ema = 0.0f;
    int nr = 0;                                  // ABSOLUTE next-ready step
    uint32_t bits = 0;
    float td1, td2, tam;

    for (int k = 0; k < ntiles; ++k) {
        if (k < ntiles - 2)       asm volatile("s_waitcnt vmcnt(32)" ::: "memory");
        else if (k == ntiles - 2) asm volatile("s_waitcnt vmcnt(16)" ::: "memory");
        else                      asm volatile("s_waitcnt vmcnt(0)"  ::: "memory");
        __builtin_amdgcn_sched_barrier(0);

        const int slot = k & (DEPTH - 1);
        const int tb = k * TS;

        if (k == 0) {
            // bit-exact t==0 seeding: ema = xt(0); step 0 then computes
            // d1=0, E_0=xt, d2=0 -> matches reference exactly.
            float x0 = lds[0][0][lane];
            ema = fastAll ? x0 : (x0 * gf);
        } else if ((k & simask) == 0) {
            int c = k >> lsi;
            emas[(size_t)c * N + i] = ema;
            nrs[(size_t)c * N + i] = nr;
        }

        if (fastAll) {
            float Ab[8], Bb[8];
#pragma unroll
            for (int j = 0; j < 8; ++j) Ab[j] = lds[slot][j][lane];        // batch 0
#pragma unroll
            for (int j = 0; j < 8; ++j) Bb[j] = lds[slot][8 + j][lane];    // batch 1
            FA_ASM8(Ab);                                                   // steps 0-7
#pragma unroll
            for (int j = 0; j < 8; ++j) Ab[j] = lds[slot][16 + j][lane];   // batch 2
            FA_ASM8(Bb);                                                   // 8-15
#pragma unroll
            for (int j = 0; j < 8; ++j) Bb[j] = lds[slot][24 + j][lane];   // batch 3
            FA_ASM8(Ab);                                                   // 16-23
#pragma unroll
            for (int j = 0; j < 8; ++j) Ab[j] = lds[slot][32 + j][lane];   // batch 4
            FA_ASM8(Bb);                                                   // 24-31
            FA_RESOLVE(tb);                                                // window 0
#pragma unroll
            for (int j = 0; j < 8; ++j) Bb[j] = lds[slot][40 + j][lane];   // batch 5
            FA_ASM8(Ab);                                                   // 32-39
#pragma unroll
            for (int j = 0; j < 8; ++j) Ab[j] = lds[slot][48 + j][lane];   // batch 6
            FA_ASM8(Bb);                                                   // 40-47
#pragma unroll
            for (int j = 0; j < 8; ++j) Bb[j] = lds[slot][56 + j][lane];   // batch 7
            FA_ASM8(Ab);                                                   // 48-55
            FA_ASM8(Bb);                                                   // 56-63
            FA_RESOLVE(tb + 32);                                           // window 1
        } else {
            float ra[8], rb[8];
#pragma unroll
            for (int j = 0; j < 8; ++j) ra[j] = lds[slot][j][lane];
#pragma unroll
            for (int t8 = 0; t8 < TS / 8; ++t8) {
                if (t8 < TS / 8 - 1) {
#pragma unroll
                    for (int j = 0; j < 8; ++j)
                        rb[j] = lds[slot][(t8 + 1) * 8 + j][lane];
                }
#pragma unroll
                for (int j = 0; j < 8; ++j) {
                    const int t = tb + t8 * 8 + j;
                    float xt = ra[j] * gf;
                    float d1 = xt - ema;
                    float am = alpha * d1;
                    ema = ema + am;
                    float d2 = xt - ema;
                    float av = Af * d2;
                    float vc = vbf - av;
                    float dv = vc - vbf;
                    bool cross = fabsf(dv) >= thf;
                    bool tge = t >= nr;
                    bool fired = cross && tge;
                    nr = fired ? (t + 1 + rs) : nr;
                }
#pragma unroll
                for (int j = 0; j < 8; ++j) ra[j] = rb[j];
            }
        }

        if (k + 3 < ntiles) ISSUE_TILE(k + 3);
    }
#undef ISSUE_TILE
}

__global__ __launch_bounds__(256)
void fa_emit_kernel(const float* __restrict__ x,
                    const float* __restrict__ vb,
                    const float* __restrict__ A,
                    const float* __restrict__ th,
                    const float* __restrict__ gain,
                    const float* __restrict__ tref,
                    const float* __restrict__ emas,
                    const int*   __restrict__ nrs,
                    float* __restrict__ out,
                    int B, int T, int F, int nchunks, int lchunk) {
#pragma clang fp contract(off)
    int N = B * F;
    int tid = blockIdx.x * blockDim.x + threadIdx.x;
    if (tid >= N * nchunks) return;
    int i = tid % N;
    int k = tid / N;
    int f = i % F;
    int b = i / F;
    const float vbf = vb[f], Af = A[f], thf = th[f], gf = gain[f];
    const float alpha = 0.001f;
    int rs = (int)fmaxf(ceilf(tref[f] / 0.05f), 1.0f);

    const float* xp = x + (size_t)b * T * F + f;
    float* va_out   = out + (size_t)b * (T + 1) * F + f;
    float* sp_out   = out + (size_t)B * (T + 1) * F + (size_t)b * (T + 1) * F + f;

    int tbeg = k * lchunk;
    int tend = tbeg + lchunk;
    if (tend > T) tend = T;

    float cur[K2_UNROLL], nxt[K2_UNROLL];
#pragma unroll
    for (int u = 0; u < K2_UNROLL; ++u) cur[u] = xp[(size_t)(tbeg + u) * F];

    float ema;
    int nr;
    if (k == 0) {
        ema = cur[0] * gf;     // t==0 seeding trick (see K1)
        nr = 0;
        va_out[0] = vbf;       // va_trace[:,0,:] = vb
    } else {
        ema = emas[(size_t)k * N + i];
        nr = nrs[(size_t)k * N + i];
    }

    float last_sp = 0.0f;
    for (int t0 = tbeg; t0 < tend; t0 += K2_UNROLL) {
        if (t0 + K2_UNROLL < tend) {
#pragma unroll
            for (int u = 0; u < K2_UNROLL; ++u)
                nxt[u] = xp[(size_t)(t0 + K2_UNROLL + u) * F];
        }
#pragma unroll
        for (int u = 0; u < K2_UNROLL; ++u) {
            int t = t0 + u;
            float xt = cur[u] * gf;
            float d1 = xt - ema;
            float am = alpha * d1;
            ema = ema + am;
            float d2 = xt - ema;
            float av = Af * d2;
            float vc = vbf - av;       // va_cand
            float dv = vc - vbf;
            bool cross = fabsf(dv) >= thf;
            bool tge = t >= nr;
            bool fired = cross && tge;
            float va_next = (cross || !tge) ? vbf : vc;
            nr = fired ? (t + 1 + rs) : nr;
            float spv = fired ? 1.0f : 0.0f;
            va_out[(size_t)(t + 1) * F] = va_next;
            sp_out[(size_t)t * F] = spv;
            last_sp = spv;
        }
#pragma unroll
        for (int u = 0; u < K2_UNROLL; ++u) cur[u] = nxt[u];
    }
    if (tend == T) sp_out[(size_t)T * F] = last_sp;   // spikes[:,T,:] = fired_{T-1}
}

// Fallback: monolithic (used only if ws too small / shape odd).
__global__ __launch_bounds__(64, 1)
void fa_neuron_mono(const float* __restrict__ x,
                    const float* __restrict__ vb,
                    const float* __restrict__ A,
                    const float* __restrict__ th,
                    const float* __restrict__ gain,
                    const float* __restrict__ tref,
                    float* __restrict__ out,
                    int B, int T, int F) {
#pragma clang fp contract(off)
    int tid = blockIdx.x * blockDim.x + threadIdx.x;
    if (tid >= B * F) return;
    int f = tid % F;
    int b = tid / F;
    const float vbf = vb[f], Af = A[f], thf = th[f], gf = gain[f];
    const float alpha = 0.001f;
    int rs = (int)fmaxf(ceilf(tref[f] / 0.05f), 1.0f);
    const float* xp = x + (size_t)b * T * F + f;
    float* va_out   = out + (size_t)b * (T + 1) * F + f;
    float* sp_out   = out + (size_t)B * (T + 1) * F + (size_t)b * (T + 1) * F + f;
    va_out[0] = vbf;
    float ema = 0.0f;
    int nr = 0;
    for (int t = 0; t < T; ++t) {
        float xt = xp[(size_t)t * F] * gf;
        if (t == 0) {
            ema = xt;
        } else {
            float d1 = xt - ema;
            float am = alpha * d1;
            ema = ema + am;
        }
        float d2 = xt - ema;
        float av = Af * d2;
        float vc = vbf - av;
        float dv = vc - vbf;
        bool cross = fabsf(dv) >= thf;
        bool tge = t >= nr;
        bool fired = cross && tge;
        float va_next = (cross || !tge) ? vbf : vc;
        nr = fired ? (t + 1 + rs) : nr;
        float spv = fired ? 1.0f : 0.0f;
        va_out[(size_t)(t + 1) * F] = va_next;
        sp_out[(size_t)t * F] = spv;
        if (t == T - 1) sp_out[(size_t)T * F] = spv;
    }
}

extern "C" void kernel_launch(void* const* d_in, const int* in_sizes, int n_in,
                              void* d_out, int out_size, void* d_ws, size_t ws_size,
                              hipStream_t stream) {
    const float* x    = (const float*)d_in[0];
    const float* vb   = (const float*)d_in[1];
    const float* A    = (const float*)d_in[2];
    const float* th   = (const float*)d_in[3];
    const float* gain = (const float*)d_in[4];
    const float* tref = (const float*)d_in[5];
    float* out = (float*)d_out;

    int F = in_sizes[1];                                   // 512
    long long BF = (long long)out_size / 2 - in_sizes[0];  // B*F
    int B = (int)(BF / F);                                 // 16
    int T = (int)(in_sizes[0] / BF);                       // 4096
    int N = B * F;

    // pick chunk size: 128 (2 tiles) if workspace allows, else 256 (4 tiles)
    int lchunk = 2 * TS, lsi = 1;
    int nchunks = (T + lchunk - 1) / lchunk;
    size_t ws_need = (size_t)nchunks * N * (sizeof(float) + sizeof(int));
    if (ws_size < ws_need) {
        lchunk = 4 * TS; lsi = 2;
        nchunks = (T + lchunk - 1) / lchunk;
        ws_need = (size_t)nchunks * N * (sizeof(float) + sizeof(int));
    }

    bool tiled_ok = (ws_size >= ws_need) && (T % lchunk == 0) &&
                    (T % TS == 0) && (T / TS >= 4) && (F % 64 == 0) &&
                    (lchunk % K2_UNROLL == 0);

    if (!tiled_ok) {
        int block = 64;
        int grid = (N + block - 1) / block;
        fa_neuron_mono<<<grid, block, 0, stream>>>(x, vb, A, th, gain, tref, out, B, T, F);
        return;
    }

    float* emas = (float*)d_ws;
    int*   nrs  = (int*)(emas + (size_t)nchunks * N);

    {
        int block = 64;
        int grid = N / 64;   // one 64-chain group per block
        fa_scan_kernel<<<grid, block, 0, stream>>>(x, vb, A, th, gain, tref,
                                                   emas, nrs, B, T, F, lsi);
    }
    {
        long long total = (long long)N * nchunks;
        int block = 256;
        int grid = (int)((total + block - 1) / block);
        fa_emit_kernel<<<grid, block, 0, stream>>>(x, vb, A, th, gain, tref,
                                                   emas, nrs, out, B, T, F,
                                                   nchunks, lchunk);
    }
}